// Round 8
// baseline (181.874 us; speedup 1.0000x reference)
//
#include <hip/hip_runtime.h>
#include <cmath>

#define S_   128
#define W_   64
#define D_   200
#define H_   50
#define OUT_ 5

// ---------------------------------------------------------------------------
// Kernel 1: one block per sentence (conv+pool commuted into the projection).
// ---------------------------------------------------------------------------
__global__ __launch_bounds__(256) void k_sent(
    const int* __restrict__ doc, const float* __restrict__ emb,
    const float* __restrict__ w_word, const float* __restrict__ b_word,
    const float* __restrict__ cw1, const float* __restrict__ cb1,
    const float* __restrict__ cw2, const float* __restrict__ cb2,
    const float* __restrict__ cw3, const float* __restrict__ cb3,
    const float* __restrict__ Wi, const float* __restrict__ bi,
    const float* __restrict__ Wf, const float* __restrict__ bf,
    const float* __restrict__ Wr, const float* __restrict__ br,
    float* __restrict__ Xout)   // [3][S_][H_]
{
    const int s   = blockIdx.x;
    const int tid = threadIdx.x;

    __shared__ int   drow[W_];
    __shared__ float vec[5][D_];     // full sum, E0, E1, E62, E63
    __shared__ float q[5][H_];       // w_word @ each of the above
    __shared__ float m[6][H_ + 2];   // the 6 window means
    __shared__ float reps_sh[H_];

    if (tid < W_) drow[tid] = doc[s * W_ + tid];
    __syncthreads();

    if (tid < D_) {
        const int d = tid;
        float acc = 0.f;
        for (int u = 0; u < W_; ++u)
            acc += emb[(size_t)drow[u] * D_ + d];
        vec[0][d] = acc;
        vec[1][d] = emb[(size_t)drow[0]      * D_ + d];
        vec[2][d] = emb[(size_t)drow[1]      * D_ + d];
        vec[3][d] = emb[(size_t)drow[W_ - 2] * D_ + d];
        vec[4][d] = emb[(size_t)drow[W_ - 1] * D_ + d];
    }
    __syncthreads();

    if (tid < 5 * H_) {
        const int v = tid / H_, h = tid % H_;
        const float* wr = w_word + h * D_;
        float acc = 0.f;
        for (int d = 0; d < D_; ++d) acc += wr[d] * vec[v][d];
        q[v][h] = acc;
    }
    __syncthreads();

    if (tid < H_) {
        const int h = tid;
        const float qf = q[0][h], q0 = q[1][h], q1 = q[2][h],
                    q62 = q[3][h], q63 = q[4][h];
        const float bw = b_word[h];
        m[0][h] = qf               * (1.f / 64.f) + bw;
        m[1][h] = (qf - q63)       * (1.f / 63.f) + bw;
        m[2][h] = (qf - q0)        * (1.f / 63.f) + bw;
        m[3][h] = (qf - q62 - q63) * (1.f / 62.f) + bw;
        m[4][h] = (qf - q0  - q63) * (1.f / 62.f) + bw;
        m[5][h] = (qf - q0  - q1)  * (1.f / 62.f) + bw;
    }
    __syncthreads();

    if (tid < H_) {
        const int o = tid;
        float a1 = cb1[o], a2 = cb2[o], a3 = cb3[o];
        for (int i = 0; i < H_; ++i) {
            a1 += cw1[o * H_ + i] * m[0][i];
            const float* c2 = cw2 + (o * H_ + i) * 2;
            a2 += c2[0] * m[1][i] + c2[1] * m[2][i];
            const float* c3 = cw3 + (o * H_ + i) * 3;
            a3 += c3[0] * m[3][i] + c3[1] * m[4][i] + c3[2] * m[5][i];
        }
        reps_sh[o] = (tanhf(a1) + tanhf(a2) + tanhf(a3)) * (1.f / 3.f);
    }
    __syncthreads();

    if (tid < 3 * H_) {
        const int g = tid / H_, o = tid % H_;
        const float* Wg = (g == 0) ? Wi : (g == 1) ? Wf : Wr;
        const float* bg = (g == 0) ? bi : (g == 1) ? bf : br;
        float acc = bg[o];
        for (int j = 0; j < H_; ++j) acc += Wg[o * H_ + j] * reps_sh[j];
        Xout[(g * S_ + s) * H_ + o] = acc;
    }
}

// ---------------------------------------------------------------------------
// Kernel 2 (v2): single-wave GRNN scan. Lane o owns h[o] and the o-th row of
// Ui/Uf/Ur in registers (full static unroll). h is broadcast lane->all via
// __shfl (DS pipe, overlaps the 150 VALU FMAs). No LDS, no barriers.
// Fast sigmoid/tanh via v_exp_f32 (no libm tanhf on the critical path).
// ---------------------------------------------------------------------------
__device__ __forceinline__ float tanh_fast(float x) {
    float e = __expf(2.f * x);
    return (e - 1.f) / (e + 1.f);
}

__global__ __launch_bounds__(64) void k_scan(
    const float* __restrict__ X,   // [3][S_][H_]
    const float* __restrict__ Ui, const float* __restrict__ Uf,
    const float* __restrict__ Ur,
    const float* __restrict__ Wout, const float* __restrict__ bout,
    float* __restrict__ out)
{
    const int o  = threadIdx.x & 63;
    const bool act = (o < H_);

    float ui[H_], uf[H_], ur[H_];
    if (act) {
        const float2* Ui2 = reinterpret_cast<const float2*>(Ui + o * H_);
        const float2* Uf2 = reinterpret_cast<const float2*>(Uf + o * H_);
        const float2* Ur2 = reinterpret_cast<const float2*>(Ur + o * H_);
        #pragma unroll
        for (int j2 = 0; j2 < H_ / 2; ++j2) {
            float2 a = Ui2[j2], b = Uf2[j2], c = Ur2[j2];
            ui[2*j2] = a.x; ui[2*j2+1] = a.y;
            uf[2*j2] = b.x; uf[2*j2+1] = b.y;
            ur[2*j2] = c.x; ur[2*j2+1] = c.y;
        }
    } else {
        #pragma unroll
        for (int j = 0; j < H_; ++j) { ui[j] = 0.f; uf[j] = 0.f; ur[j] = 0.f; }
    }

    float h = 0.f;
    float xi = act ? X[(0 * S_ + 0) * H_ + o] : 0.f;
    float xf = act ? X[(1 * S_ + 0) * H_ + o] : 0.f;
    float xr = act ? X[(2 * S_ + 0) * H_ + o] : 0.f;

    for (int t = 0; t < S_; ++t) {
        // prefetch next step's inputs (L2-resident; hides under the FMAs)
        float nxi = 0.f, nxf = 0.f, nxr = 0.f;
        if (act && t + 1 < S_) {
            nxi = X[(0 * S_ + t + 1) * H_ + o];
            nxf = X[(1 * S_ + t + 1) * H_ + o];
            nxr = X[(2 * S_ + t + 1) * H_ + o];
        }
        float ai = xi, af = xf, ar = xr;
        #pragma unroll
        for (int j = 0; j < H_; ++j) {
            float hj = __shfl(h, j, 64);
            ai += ui[j] * hj;
            af += uf[j] * hj;
            ar += ur[j] * hj;
        }
        float gi = 1.f / (1.f + __expf(-ai));
        float gf = 1.f / (1.f + __expf(-af));
        float gg = tanh_fast(ar);
        h = tanh_fast(gi * gg + gf * h);
        xi = nxi; xf = nxf; xr = nxr;
    }

    // output head: logits in lanes 0..4, softmax computed redundantly in-wave
    float logit = (o < OUT_) ? bout[o] : 0.f;
    #pragma unroll
    for (int j = 0; j < H_; ++j) {
        float hj = __shfl(h, j, 64);
        if (o < OUT_) logit += Wout[o * H_ + j] * hj;
    }
    float l0 = __shfl(logit, 0, 64), l1 = __shfl(logit, 1, 64),
          l2 = __shfl(logit, 2, 64), l3 = __shfl(logit, 3, 64),
          l4 = __shfl(logit, 4, 64);
    float mx = fmaxf(fmaxf(fmaxf(l0, l1), fmaxf(l2, l3)), l4);
    float e0 = __expf(l0 - mx), e1 = __expf(l1 - mx), e2 = __expf(l2 - mx),
          e3 = __expf(l3 - mx), e4 = __expf(l4 - mx);
    float s = e0 + e1 + e2 + e3 + e4;
    if (o == 0) {
        out[0] = e0 / s; out[1] = e1 / s; out[2] = e2 / s;
        out[3] = e3 / s; out[4] = e4 / s;
    }
}

extern "C" void kernel_launch(void* const* d_in, const int* in_sizes, int n_in,
                              void* d_out, int out_size, void* d_ws, size_t ws_size,
                              hipStream_t stream) {
    (void)in_sizes; (void)n_in; (void)out_size; (void)ws_size;

    const int*   doc    = (const int*)  d_in[0];
    const float* emb    = (const float*)d_in[1];
    const float* w_word = (const float*)d_in[2];
    const float* b_word = (const float*)d_in[3];
    const float* cw1    = (const float*)d_in[4];
    const float* cb1    = (const float*)d_in[5];
    const float* cw2    = (const float*)d_in[6];
    const float* cb2    = (const float*)d_in[7];
    const float* cw3    = (const float*)d_in[8];
    const float* cb3    = (const float*)d_in[9];
    const float* Wi     = (const float*)d_in[10];
    const float* Ui     = (const float*)d_in[11];
    const float* bi     = (const float*)d_in[12];
    const float* Wf     = (const float*)d_in[13];
    const float* Uf     = (const float*)d_in[14];
    const float* bf     = (const float*)d_in[15];
    const float* Wr     = (const float*)d_in[16];
    const float* Ur     = (const float*)d_in[17];
    const float* br     = (const float*)d_in[18];
    const float* Wout   = (const float*)d_in[19];
    const float* bout   = (const float*)d_in[20];

    float* X = (float*)d_ws;                 // [3][S_][H_] = 76.8 KB
    float* out = (float*)d_out;

    k_sent<<<S_, 256, 0, stream>>>(doc, emb, w_word, b_word,
                                   cw1, cb1, cw2, cb2, cw3, cb3,
                                   Wi, bi, Wf, bf, Wr, br, X);
    k_scan<<<1, 64, 0, stream>>>(X, Ui, Uf, Ur, Wout, bout, out);
}

// Round 11
// 110.010 us; speedup vs baseline: 1.6532x; 1.6532x over previous
//
#include <hip/hip_runtime.h>
#include <cmath>

#define S_   128
#define W_   64
#define D_   200
#define H_   50
#define OUT_ 5

// ---------------------------------------------------------------------------
// Kernel 1: one block per sentence (conv+pool commuted into the projection).
// ---------------------------------------------------------------------------
__global__ __launch_bounds__(256) void k_sent(
    const int* __restrict__ doc, const float* __restrict__ emb,
    const float* __restrict__ w_word, const float* __restrict__ b_word,
    const float* __restrict__ cw1, const float* __restrict__ cb1,
    const float* __restrict__ cw2, const float* __restrict__ cb2,
    const float* __restrict__ cw3, const float* __restrict__ cb3,
    const float* __restrict__ Wi, const float* __restrict__ bi,
    const float* __restrict__ Wf, const float* __restrict__ bf,
    const float* __restrict__ Wr, const float* __restrict__ br,
    float* __restrict__ Xout)   // [3][S_][H_]
{
    const int s   = blockIdx.x;
    const int tid = threadIdx.x;

    __shared__ int   drow[W_];
    __shared__ float vec[5][D_];     // full sum, E0, E1, E62, E63
    __shared__ float q[5][H_];       // w_word @ each of the above
    __shared__ float m[6][H_ + 2];   // the 6 window means
    __shared__ float reps_sh[H_];

    if (tid < W_) drow[tid] = doc[s * W_ + tid];
    __syncthreads();

    if (tid < D_) {
        const int d = tid;
        float acc = 0.f;
        for (int u = 0; u < W_; ++u)
            acc += emb[(size_t)drow[u] * D_ + d];
        vec[0][d] = acc;
        vec[1][d] = emb[(size_t)drow[0]      * D_ + d];
        vec[2][d] = emb[(size_t)drow[1]      * D_ + d];
        vec[3][d] = emb[(size_t)drow[W_ - 2] * D_ + d];
        vec[4][d] = emb[(size_t)drow[W_ - 1] * D_ + d];
    }
    __syncthreads();

    if (tid < 5 * H_) {
        const int v = tid / H_, h = tid % H_;
        const float* wr = w_word + h * D_;
        float acc = 0.f;
        for (int d = 0; d < D_; ++d) acc += wr[d] * vec[v][d];
        q[v][h] = acc;
    }
    __syncthreads();

    if (tid < H_) {
        const int h = tid;
        const float qf = q[0][h], q0 = q[1][h], q1 = q[2][h],
                    q62 = q[3][h], q63 = q[4][h];
        const float bw = b_word[h];
        m[0][h] = qf               * (1.f / 64.f) + bw;
        m[1][h] = (qf - q63)       * (1.f / 63.f) + bw;
        m[2][h] = (qf - q0)        * (1.f / 63.f) + bw;
        m[3][h] = (qf - q62 - q63) * (1.f / 62.f) + bw;
        m[4][h] = (qf - q0  - q63) * (1.f / 62.f) + bw;
        m[5][h] = (qf - q0  - q1)  * (1.f / 62.f) + bw;
    }
    __syncthreads();

    if (tid < H_) {
        const int o = tid;
        float a1 = cb1[o], a2 = cb2[o], a3 = cb3[o];
        for (int i = 0; i < H_; ++i) {
            a1 += cw1[o * H_ + i] * m[0][i];
            const float* c2 = cw2 + (o * H_ + i) * 2;
            a2 += c2[0] * m[1][i] + c2[1] * m[2][i];
            const float* c3 = cw3 + (o * H_ + i) * 3;
            a3 += c3[0] * m[3][i] + c3[1] * m[4][i] + c3[2] * m[5][i];
        }
        reps_sh[o] = (tanhf(a1) + tanhf(a2) + tanhf(a3)) * (1.f / 3.f);
    }
    __syncthreads();

    if (tid < 3 * H_) {
        const int g = tid / H_, o = tid % H_;
        const float* Wg = (g == 0) ? Wi : (g == 1) ? Wf : Wr;
        const float* bg = (g == 0) ? bi : (g == 1) ? bf : br;
        float acc = bg[o];
        for (int j = 0; j < H_; ++j) acc += Wg[o * H_ + j] * reps_sh[j];
        Xout[(g * S_ + s) * H_ + o] = acc;
    }
}

// ---------------------------------------------------------------------------
// Kernel 2 (v3): single-wave GRNN scan, register-resident U.
// __launch_bounds__(64, 1): 1 wave/EU -> full VGPR file, no spill (R8's
// regression was the compiler capping at 112 VGPRs and spilling ~70 values
// to scratch, re-read every step). Uniform code on all 64 lanes via clamped
// row index; lanes >= H_ compute garbage that is never read (readlane only
// pulls j < 50, store only from lane 0).
// ---------------------------------------------------------------------------
__device__ __forceinline__ float tanh_fast(float x) {
    float e = __expf(2.f * x);
    return (e - 1.f) / (e + 1.f);
}

__global__ __launch_bounds__(64, 1) void k_scan(
    const float* __restrict__ X,   // [3][S_][H_]
    const float* __restrict__ Ui, const float* __restrict__ Uf,
    const float* __restrict__ Ur,
    const float* __restrict__ Wout, const float* __restrict__ bout,
    float* __restrict__ out)
{
    const int o  = threadIdx.x & 63;
    const int ro = (o < H_) ? o : (H_ - 1);   // clamped: all lanes in-bounds

    float ui[H_], uf[H_], ur[H_];
    {
        const float* Uir = Ui + ro * H_;
        const float* Ufr = Uf + ro * H_;
        const float* Urr = Ur + ro * H_;
        #pragma unroll
        for (int j = 0; j < H_; ++j) {
            ui[j] = Uir[j];
            uf[j] = Ufr[j];
            ur[j] = Urr[j];
        }
    }

    float h  = 0.f;
    float xi = X[(0 * S_ + 0) * H_ + ro];
    float xf = X[(1 * S_ + 0) * H_ + ro];
    float xr = X[(2 * S_ + 0) * H_ + ro];

    for (int t = 0; t < S_; ++t) {
        const int tn = (t + 1 < S_) ? (t + 1) : (S_ - 1);   // clamped prefetch
        float nxi = X[(0 * S_ + tn) * H_ + ro];
        float nxf = X[(1 * S_ + tn) * H_ + ro];
        float nxr = X[(2 * S_ + tn) * H_ + ro];

        float ai = xi, af = xf, ar = xr;
        #pragma unroll
        for (int j = 0; j < H_; ++j) {
            float hj = __shfl(h, j, 64);
            ai += ui[j] * hj;
            af += uf[j] * hj;
            ar += ur[j] * hj;
        }
        float gi = 1.f / (1.f + __expf(-ai));
        float gf = 1.f / (1.f + __expf(-af));
        float gg = tanh_fast(ar);
        h = tanh_fast(gi * gg + gf * h);
        xi = nxi; xf = nxf; xr = nxr;
    }

    // output head: logits in lanes 0..4, softmax redundantly in-wave
    float logit = (o < OUT_) ? bout[o] : 0.f;
    const float* wrow = Wout + ((o < OUT_) ? o : 0) * H_;
    #pragma unroll
    for (int j = 0; j < H_; ++j) {
        float hj = __shfl(h, j, 64);
        logit += wrow[j] * hj;
    }
    float l0 = __shfl(logit, 0, 64), l1 = __shfl(logit, 1, 64),
          l2 = __shfl(logit, 2, 64), l3 = __shfl(logit, 3, 64),
          l4 = __shfl(logit, 4, 64);
    float mx = fmaxf(fmaxf(fmaxf(l0, l1), fmaxf(l2, l3)), l4);
    float e0 = __expf(l0 - mx), e1 = __expf(l1 - mx), e2 = __expf(l2 - mx),
          e3 = __expf(l3 - mx), e4 = __expf(l4 - mx);
    float s = e0 + e1 + e2 + e3 + e4;
    if (o == 0) {
        out[0] = e0 / s; out[1] = e1 / s; out[2] = e2 / s;
        out[3] = e3 / s; out[4] = e4 / s;
    }
}

extern "C" void kernel_launch(void* const* d_in, const int* in_sizes, int n_in,
                              void* d_out, int out_size, void* d_ws, size_t ws_size,
                              hipStream_t stream) {
    (void)in_sizes; (void)n_in; (void)out_size; (void)ws_size;

    const int*   doc    = (const int*)  d_in[0];
    const float* emb    = (const float*)d_in[1];
    const float* w_word = (const float*)d_in[2];
    const float* b_word = (const float*)d_in[3];
    const float* cw1    = (const float*)d_in[4];
    const float* cb1    = (const float*)d_in[5];
    const float* cw2    = (const float*)d_in[6];
    const float* cb2    = (const float*)d_in[7];
    const float* cw3    = (const float*)d_in[8];
    const float* cb3    = (const float*)d_in[9];
    const float* Wi     = (const float*)d_in[10];
    const float* Ui     = (const float*)d_in[11];
    const float* bi     = (const float*)d_in[12];
    const float* Wf     = (const float*)d_in[13];
    const float* Uf     = (const float*)d_in[14];
    const float* bf     = (const float*)d_in[15];
    const float* Wr     = (const float*)d_in[16];
    const float* Ur     = (const float*)d_in[17];
    const float* br     = (const float*)d_in[18];
    const float* Wout   = (const float*)d_in[19];
    const float* bout   = (const float*)d_in[20];

    float* X = (float*)d_ws;                 // [3][S_][H_] = 76.8 KB
    float* out = (float*)d_out;

    k_sent<<<S_, 256, 0, stream>>>(doc, emb, w_word, b_word,
                                   cw1, cb1, cw2, cb2, cw3, cb3,
                                   Wi, bi, Wf, bf, Wr, br, X);
    k_scan<<<1, 64, 0, stream>>>(X, Ui, Uf, Ur, Wout, bout, out);
}

// Round 12
// 104.484 us; speedup vs baseline: 1.7407x; 1.0529x over previous
//
#include <hip/hip_runtime.h>
#include <cmath>

#define S_   128
#define W_   64
#define D_   200
#define H_   50
#define OUT_ 5

// ---------------------------------------------------------------------------
// Kernel 1: one block per sentence (conv+pool commuted into the projection).
// ---------------------------------------------------------------------------
__global__ __launch_bounds__(256) void k_sent(
    const int* __restrict__ doc, const float* __restrict__ emb,
    const float* __restrict__ w_word, const float* __restrict__ b_word,
    const float* __restrict__ cw1, const float* __restrict__ cb1,
    const float* __restrict__ cw2, const float* __restrict__ cb2,
    const float* __restrict__ cw3, const float* __restrict__ cb3,
    const float* __restrict__ Wi, const float* __restrict__ bi,
    const float* __restrict__ Wf, const float* __restrict__ bf,
    const float* __restrict__ Wr, const float* __restrict__ br,
    float* __restrict__ Xout)   // [3][S_][H_]
{
    const int s   = blockIdx.x;
    const int tid = threadIdx.x;

    __shared__ int   drow[W_];
    __shared__ float vec[5][D_];     // full sum, E0, E1, E62, E63
    __shared__ float q[5][H_];       // w_word @ each of the above
    __shared__ float m[6][H_ + 2];   // the 6 window means
    __shared__ float reps_sh[H_];

    if (tid < W_) drow[tid] = doc[s * W_ + tid];
    __syncthreads();

    if (tid < D_) {
        const int d = tid;
        float acc = 0.f;
        for (int u = 0; u < W_; ++u)
            acc += emb[(size_t)drow[u] * D_ + d];
        vec[0][d] = acc;
        vec[1][d] = emb[(size_t)drow[0]      * D_ + d];
        vec[2][d] = emb[(size_t)drow[1]      * D_ + d];
        vec[3][d] = emb[(size_t)drow[W_ - 2] * D_ + d];
        vec[4][d] = emb[(size_t)drow[W_ - 1] * D_ + d];
    }
    __syncthreads();

    if (tid < 5 * H_) {
        const int v = tid / H_, h = tid % H_;
        const float* wr = w_word + h * D_;
        float acc = 0.f;
        for (int d = 0; d < D_; ++d) acc += wr[d] * vec[v][d];
        q[v][h] = acc;
    }
    __syncthreads();

    if (tid < H_) {
        const int h = tid;
        const float qf = q[0][h], q0 = q[1][h], q1 = q[2][h],
                    q62 = q[3][h], q63 = q[4][h];
        const float bw = b_word[h];
        m[0][h] = qf               * (1.f / 64.f) + bw;
        m[1][h] = (qf - q63)       * (1.f / 63.f) + bw;
        m[2][h] = (qf - q0)        * (1.f / 63.f) + bw;
        m[3][h] = (qf - q62 - q63) * (1.f / 62.f) + bw;
        m[4][h] = (qf - q0  - q63) * (1.f / 62.f) + bw;
        m[5][h] = (qf - q0  - q1)  * (1.f / 62.f) + bw;
    }
    __syncthreads();

    if (tid < H_) {
        const int o = tid;
        float a1 = cb1[o], a2 = cb2[o], a3 = cb3[o];
        for (int i = 0; i < H_; ++i) {
            a1 += cw1[o * H_ + i] * m[0][i];
            const float* c2 = cw2 + (o * H_ + i) * 2;
            a2 += c2[0] * m[1][i] + c2[1] * m[2][i];
            const float* c3 = cw3 + (o * H_ + i) * 3;
            a3 += c3[0] * m[3][i] + c3[1] * m[4][i] + c3[2] * m[5][i];
        }
        reps_sh[o] = (tanhf(a1) + tanhf(a2) + tanhf(a3)) * (1.f / 3.f);
    }
    __syncthreads();

    if (tid < 3 * H_) {
        const int g = tid / H_, o = tid % H_;
        const float* Wg = (g == 0) ? Wi : (g == 1) ? Wf : Wr;
        const float* bg = (g == 0) ? bi : (g == 1) ? bf : br;
        float acc = bg[o];
        for (int j = 0; j < H_; ++j) acc += Wg[o * H_ + j] * reps_sh[j];
        Xout[(g * S_ + s) * H_ + o] = acc;
    }
}

// ---------------------------------------------------------------------------
// Kernel 2 (v4): single-wave GRNN scan.
// amdgpu_waves_per_eu(1,1): max 1 wave/EU -> allocator may use the full
// register file (R11 showed __launch_bounds__(64,1) alone leaves the
// occupancy heuristic capping at ~132 VGPRs -> U reloaded every step).
// h broadcast via readlane (compile-time lane index -> SGPR, VALU pipe,
// no DS latency, no VGPR pressure from 50 live shfl results).
// ---------------------------------------------------------------------------
__device__ __forceinline__ float tanh_fast(float x) {
    float e = __expf(2.f * x);
    return (e - 1.f) / (e + 1.f);
}

__device__ __forceinline__ float bcast(float v, int lane) {
    return __int_as_float(__builtin_amdgcn_readlane(__float_as_int(v), lane));
}

__global__ __launch_bounds__(64)
__attribute__((amdgpu_waves_per_eu(1, 1)))
void k_scan(
    const float* __restrict__ X,   // [3][S_][H_]
    const float* __restrict__ Ui, const float* __restrict__ Uf,
    const float* __restrict__ Ur,
    const float* __restrict__ Wout, const float* __restrict__ bout,
    float* __restrict__ out)
{
    const int o  = threadIdx.x & 63;
    const int ro = (o < H_) ? o : (H_ - 1);   // clamped: all lanes in-bounds

    float ui[H_], uf[H_], ur[H_];
    {
        const float* Uir = Ui + ro * H_;
        const float* Ufr = Uf + ro * H_;
        const float* Urr = Ur + ro * H_;
        #pragma unroll
        for (int j = 0; j < H_; ++j) {
            ui[j] = Uir[j];
            uf[j] = Ufr[j];
            ur[j] = Urr[j];
        }
    }

    float h  = 0.f;
    float xi = X[(0 * S_ + 0) * H_ + ro];
    float xf = X[(1 * S_ + 0) * H_ + ro];
    float xr = X[(2 * S_ + 0) * H_ + ro];

    for (int t = 0; t < S_; ++t) {
        const int tn = (t + 1 < S_) ? (t + 1) : (S_ - 1);   // clamped prefetch
        float nxi = X[(0 * S_ + tn) * H_ + ro];
        float nxf = X[(1 * S_ + tn) * H_ + ro];
        float nxr = X[(2 * S_ + tn) * H_ + ro];

        float ai = xi, af = xf, ar = xr;
        #pragma unroll
        for (int j = 0; j < H_; ++j) {
            float hj = bcast(h, j);          // SGPR broadcast, VALU pipe
            ai += ui[j] * hj;
            af += uf[j] * hj;
            ar += ur[j] * hj;
        }
        float gi = 1.f / (1.f + __expf(-ai));
        float gf = 1.f / (1.f + __expf(-af));
        float gg = tanh_fast(ar);
        h = tanh_fast(gi * gg + gf * h);
        xi = nxi; xf = nxf; xr = nxr;
    }

    // output head: logits in lanes 0..4, softmax redundantly in-wave
    float logit = (o < OUT_) ? bout[o] : 0.f;
    const float* wrow = Wout + ((o < OUT_) ? o : 0) * H_;
    #pragma unroll
    for (int j = 0; j < H_; ++j) {
        float hj = bcast(h, j);
        logit += wrow[j] * hj;
    }
    float l0 = bcast(logit, 0), l1 = bcast(logit, 1), l2 = bcast(logit, 2),
          l3 = bcast(logit, 3), l4 = bcast(logit, 4);
    float mx = fmaxf(fmaxf(fmaxf(l0, l1), fmaxf(l2, l3)), l4);
    float e0 = __expf(l0 - mx), e1 = __expf(l1 - mx), e2 = __expf(l2 - mx),
          e3 = __expf(l3 - mx), e4 = __expf(l4 - mx);
    float s = e0 + e1 + e2 + e3 + e4;
    if (o == 0) {
        out[0] = e0 / s; out[1] = e1 / s; out[2] = e2 / s;
        out[3] = e3 / s; out[4] = e4 / s;
    }
}

extern "C" void kernel_launch(void* const* d_in, const int* in_sizes, int n_in,
                              void* d_out, int out_size, void* d_ws, size_t ws_size,
                              hipStream_t stream) {
    (void)in_sizes; (void)n_in; (void)out_size; (void)ws_size;

    const int*   doc    = (const int*)  d_in[0];
    const float* emb    = (const float*)d_in[1];
    const float* w_word = (const float*)d_in[2];
    const float* b_word = (const float*)d_in[3];
    const float* cw1    = (const float*)d_in[4];
    const float* cb1    = (const float*)d_in[5];
    const float* cw2    = (const float*)d_in[6];
    const float* cb2    = (const float*)d_in[7];
    const float* cw3    = (const float*)d_in[8];
    const float* cb3    = (const float*)d_in[9];
    const float* Wi     = (const float*)d_in[10];
    const float* Ui     = (const float*)d_in[11];
    const float* bi     = (const float*)d_in[12];
    const float* Wf     = (const float*)d_in[13];
    const float* Uf     = (const float*)d_in[14];
    const float* bf     = (const float*)d_in[15];
    const float* Wr     = (const float*)d_in[16];
    const float* Ur     = (const float*)d_in[17];
    const float* br     = (const float*)d_in[18];
    const float* Wout   = (const float*)d_in[19];
    const float* bout   = (const float*)d_in[20];

    float* X = (float*)d_ws;                 // [3][S_][H_] = 76.8 KB
    float* out = (float*)d_out;

    k_sent<<<S_, 256, 0, stream>>>(doc, emb, w_word, b_word,
                                   cw1, cb1, cw2, cb2, cw3, cb3,
                                   Wi, bi, Wf, bf, Wr, br, X);
    k_scan<<<1, 64, 0, stream>>>(X, Ui, Uf, Ur, Wout, bout, out);
}

// Round 13
// 92.503 us; speedup vs baseline: 1.9661x; 1.1295x over previous
//
#include <hip/hip_runtime.h>
#include <cmath>

#define S_   128
#define W_   64
#define D_   200
#define H_   50
#define OUT_ 5

// ---------------------------------------------------------------------------
// Kernel 1: one block per sentence (conv+pool commuted into the projection).
// ---------------------------------------------------------------------------
__global__ __launch_bounds__(256) void k_sent(
    const int* __restrict__ doc, const float* __restrict__ emb,
    const float* __restrict__ w_word, const float* __restrict__ b_word,
    const float* __restrict__ cw1, const float* __restrict__ cb1,
    const float* __restrict__ cw2, const float* __restrict__ cb2,
    const float* __restrict__ cw3, const float* __restrict__ cb3,
    const float* __restrict__ Wi, const float* __restrict__ bi,
    const float* __restrict__ Wf, const float* __restrict__ bf,
    const float* __restrict__ Wr, const float* __restrict__ br,
    float* __restrict__ Xout)   // [3][S_][H_]
{
    const int s   = blockIdx.x;
    const int tid = threadIdx.x;

    __shared__ int   drow[W_];
    __shared__ float vec[5][D_];     // full sum, E0, E1, E62, E63
    __shared__ float q[5][H_];       // w_word @ each of the above
    __shared__ float m[6][H_ + 2];   // the 6 window means
    __shared__ float reps_sh[H_];

    if (tid < W_) drow[tid] = doc[s * W_ + tid];
    __syncthreads();

    if (tid < D_) {
        const int d = tid;
        float acc = 0.f;
        for (int u = 0; u < W_; ++u)
            acc += emb[(size_t)drow[u] * D_ + d];
        vec[0][d] = acc;
        vec[1][d] = emb[(size_t)drow[0]      * D_ + d];
        vec[2][d] = emb[(size_t)drow[1]      * D_ + d];
        vec[3][d] = emb[(size_t)drow[W_ - 2] * D_ + d];
        vec[4][d] = emb[(size_t)drow[W_ - 1] * D_ + d];
    }
    __syncthreads();

    if (tid < 5 * H_) {
        const int v = tid / H_, h = tid % H_;
        const float* wr = w_word + h * D_;
        float acc = 0.f;
        for (int d = 0; d < D_; ++d) acc += wr[d] * vec[v][d];
        q[v][h] = acc;
    }
    __syncthreads();

    if (tid < H_) {
        const int h = tid;
        const float qf = q[0][h], q0 = q[1][h], q1 = q[2][h],
                    q62 = q[3][h], q63 = q[4][h];
        const float bw = b_word[h];
        m[0][h] = qf               * (1.f / 64.f) + bw;
        m[1][h] = (qf - q63)       * (1.f / 63.f) + bw;
        m[2][h] = (qf - q0)        * (1.f / 63.f) + bw;
        m[3][h] = (qf - q62 - q63) * (1.f / 62.f) + bw;
        m[4][h] = (qf - q0  - q63) * (1.f / 62.f) + bw;
        m[5][h] = (qf - q0  - q1)  * (1.f / 62.f) + bw;
    }
    __syncthreads();

    if (tid < H_) {
        const int o = tid;
        float a1 = cb1[o], a2 = cb2[o], a3 = cb3[o];
        for (int i = 0; i < H_; ++i) {
            a1 += cw1[o * H_ + i] * m[0][i];
            const float* c2 = cw2 + (o * H_ + i) * 2;
            a2 += c2[0] * m[1][i] + c2[1] * m[2][i];
            const float* c3 = cw3 + (o * H_ + i) * 3;
            a3 += c3[0] * m[3][i] + c3[1] * m[4][i] + c3[2] * m[5][i];
        }
        reps_sh[o] = (tanhf(a1) + tanhf(a2) + tanhf(a3)) * (1.f / 3.f);
    }
    __syncthreads();

    if (tid < 3 * H_) {
        const int g = tid / H_, o = tid % H_;
        const float* Wg = (g == 0) ? Wi : (g == 1) ? Wf : Wr;
        const float* bg = (g == 0) ? bi : (g == 1) ? bf : br;
        float acc = bg[o];
        for (int j = 0; j < H_; ++j) acc += Wg[o * H_ + j] * reps_sh[j];
        Xout[(g * S_ + s) * H_ + o] = acc;
    }
}

// ---------------------------------------------------------------------------
// Kernel 2 (v5): 2-wave column-split GRNN scan.
// The allocator's de-facto VGPR budget is ~132 (measured R8/R11/R12), so 150
// register-resident U values/lane is impossible. Split the contraction dim:
// wave w holds columns [25w, 25w+25) of Ui/Uf/Ur for its output row -> 75 U
// regs/lane, fully resident. Partial sums exchanged via double-buffered LDS
// with ONE barrier per step; both waves redundantly compute gates + h_new
// (identical FP ops -> identical state). h broadcast via readlane (SGPR).
// ---------------------------------------------------------------------------
#define JW 25   // columns per wave

__device__ __forceinline__ float tanh_fast(float x) {
    float e = __expf(2.f * x);
    return (e - 1.f) / (e + 1.f);
}

__device__ __forceinline__ float bcast(float v, int lane) {
    return __int_as_float(__builtin_amdgcn_readlane(__float_as_int(v), lane));
}

__global__ __launch_bounds__(128, 1) void k_scan(
    const float* __restrict__ X,   // [3][S_][H_]
    const float* __restrict__ Ui, const float* __restrict__ Uf,
    const float* __restrict__ Ur,
    const float* __restrict__ Wout, const float* __restrict__ bout,
    float* __restrict__ out)
{
    const int tid = threadIdx.x;
    const int w   = tid >> 6;                 // wave: 0 or 1
    const int o   = tid & 63;
    const int ro  = (o < H_) ? o : (H_ - 1);  // clamped row, all lanes in-bounds
    const int jlo = w * JW;                   // this wave's column window

    // partials[parity][wave][gate][lane]  (lane dim padded to 64)
    __shared__ float part[2][2][3][64];

    float ua[JW], ub[JW], uc[JW];
    {
        const float* Uir = Ui + ro * H_ + jlo;
        const float* Ufr = Uf + ro * H_ + jlo;
        const float* Urr = Ur + ro * H_ + jlo;
        #pragma unroll
        for (int jj = 0; jj < JW; ++jj) {
            ua[jj] = Uir[jj];
            ub[jj] = Ufr[jj];
            uc[jj] = Urr[jj];
        }
    }

    float h  = 0.f;                            // lane o holds h[o] (both waves)
    float xi = X[(0 * S_ + 0) * H_ + ro];
    float xf = X[(1 * S_ + 0) * H_ + ro];
    float xr = X[(2 * S_ + 0) * H_ + ro];

    int p = 0;
    for (int t = 0; t < S_; ++t) {
        // prefetch next step's inputs (L2-resident; hides under FMAs+barrier)
        const int tn = (t + 1 < S_) ? (t + 1) : (S_ - 1);
        float nxi = X[(0 * S_ + tn) * H_ + ro];
        float nxf = X[(1 * S_ + tn) * H_ + ro];
        float nxr = X[(2 * S_ + tn) * H_ + ro];

        // partial dots over this wave's column window
        float pi = 0.f, pf = 0.f, pr = 0.f;
        #pragma unroll
        for (int jj = 0; jj < JW; ++jj) {
            float hj = bcast(h, jlo + jj);     // SGPR broadcast
            pi += ua[jj] * hj;
            pf += ub[jj] * hj;
            pr += uc[jj] * hj;
        }
        part[p][w][0][o] = pi;
        part[p][w][1][o] = pf;
        part[p][w][2][o] = pr;
        __syncthreads();

        const int v = 1 - w;                   // other wave's partials
        float ai = xi + pi + part[p][v][0][o];
        float af = xf + pf + part[p][v][1][o];
        float ar = xr + pr + part[p][v][2][o];

        float gi = 1.f / (1.f + __expf(-ai));
        float gf = 1.f / (1.f + __expf(-af));
        float gg = tanh_fast(ar);
        h = tanh_fast(gi * gg + gf * h);       // identical in both waves

        xi = nxi; xf = nxf; xr = nxr;
        p ^= 1;                                // double buffer: no 2nd barrier
    }

    // output head (both waves compute; lane/tid 0 stores)
    float logit = (o < OUT_) ? bout[o] : 0.f;
    const float* wrow = Wout + ((o < OUT_) ? o : 0) * H_;
    #pragma unroll
    for (int j = 0; j < H_; ++j) {
        float hj = bcast(h, j);
        logit += wrow[j] * hj;
    }
    float l0 = bcast(logit, 0), l1 = bcast(logit, 1), l2 = bcast(logit, 2),
          l3 = bcast(logit, 3), l4 = bcast(logit, 4);
    float mx = fmaxf(fmaxf(fmaxf(l0, l1), fmaxf(l2, l3)), l4);
    float e0 = __expf(l0 - mx), e1 = __expf(l1 - mx), e2 = __expf(l2 - mx),
          e3 = __expf(l3 - mx), e4 = __expf(l4 - mx);
    float s = e0 + e1 + e2 + e3 + e4;
    if (tid == 0) {
        out[0] = e0 / s; out[1] = e1 / s; out[2] = e2 / s;
        out[3] = e3 / s; out[4] = e4 / s;
    }
}

extern "C" void kernel_launch(void* const* d_in, const int* in_sizes, int n_in,
                              void* d_out, int out_size, void* d_ws, size_t ws_size,
                              hipStream_t stream) {
    (void)in_sizes; (void)n_in; (void)out_size; (void)ws_size;

    const int*   doc    = (const int*)  d_in[0];
    const float* emb    = (const float*)d_in[1];
    const float* w_word = (const float*)d_in[2];
    const float* b_word = (const float*)d_in[3];
    const float* cw1    = (const float*)d_in[4];
    const float* cb1    = (const float*)d_in[5];
    const float* cw2    = (const float*)d_in[6];
    const float* cb2    = (const float*)d_in[7];
    const float* cw3    = (const float*)d_in[8];
    const float* cb3    = (const float*)d_in[9];
    const float* Wi     = (const float*)d_in[10];
    const float* Ui     = (const float*)d_in[11];
    const float* bi     = (const float*)d_in[12];
    const float* Wf     = (const float*)d_in[13];
    const float* Uf     = (const float*)d_in[14];
    const float* bf     = (const float*)d_in[15];
    const float* Wr     = (const float*)d_in[16];
    const float* Ur     = (const float*)d_in[17];
    const float* br     = (const float*)d_in[18];
    const float* Wout   = (const float*)d_in[19];
    const float* bout   = (const float*)d_in[20];

    float* X = (float*)d_ws;                 // [3][S_][H_] = 76.8 KB
    float* out = (float*)d_out;

    k_sent<<<S_, 256, 0, stream>>>(doc, emb, w_word, b_word,
                                   cw1, cb1, cw2, cb2, cw3, cb3,
                                   Wi, bi, Wf, bf, Wr, br, X);
    k_scan<<<1, 128, 0, stream>>>(X, Ui, Uf, Ur, Wout, bout, out);
}

// Round 14
// 78.858 us; speedup vs baseline: 2.3064x; 1.1730x over previous
//
#include <hip/hip_runtime.h>
#include <cmath>

#define S_   128
#define W_   64
#define D_   200
#define H_   50
#define OUT_ 5

// ---------------------------------------------------------------------------
// Kernel 1: one block per sentence (conv+pool commuted into the projection).
// ---------------------------------------------------------------------------
__global__ __launch_bounds__(256) void k_sent(
    const int* __restrict__ doc, const float* __restrict__ emb,
    const float* __restrict__ w_word, const float* __restrict__ b_word,
    const float* __restrict__ cw1, const float* __restrict__ cb1,
    const float* __restrict__ cw2, const float* __restrict__ cb2,
    const float* __restrict__ cw3, const float* __restrict__ cb3,
    const float* __restrict__ Wi, const float* __restrict__ bi,
    const float* __restrict__ Wf, const float* __restrict__ bf,
    const float* __restrict__ Wr, const float* __restrict__ br,
    float* __restrict__ Xout)   // [3][S_][H_]
{
    const int s   = blockIdx.x;
    const int tid = threadIdx.x;

    __shared__ int   drow[W_];
    __shared__ float vec[5][D_];     // full sum, E0, E1, E62, E63
    __shared__ float q[5][H_];       // w_word @ each of the above
    __shared__ float m[6][H_ + 2];   // the 6 window means
    __shared__ float reps_sh[H_];

    if (tid < W_) drow[tid] = doc[s * W_ + tid];
    __syncthreads();

    if (tid < D_) {
        const int d = tid;
        float acc = 0.f;
        for (int u = 0; u < W_; ++u)
            acc += emb[(size_t)drow[u] * D_ + d];
        vec[0][d] = acc;
        vec[1][d] = emb[(size_t)drow[0]      * D_ + d];
        vec[2][d] = emb[(size_t)drow[1]      * D_ + d];
        vec[3][d] = emb[(size_t)drow[W_ - 2] * D_ + d];
        vec[4][d] = emb[(size_t)drow[W_ - 1] * D_ + d];
    }
    __syncthreads();

    if (tid < 5 * H_) {
        const int v = tid / H_, h = tid % H_;
        const float* wr = w_word + h * D_;
        float acc = 0.f;
        for (int d = 0; d < D_; ++d) acc += wr[d] * vec[v][d];
        q[v][h] = acc;
    }
    __syncthreads();

    if (tid < H_) {
        const int h = tid;
        const float qf = q[0][h], q0 = q[1][h], q1 = q[2][h],
                    q62 = q[3][h], q63 = q[4][h];
        const float bw = b_word[h];
        m[0][h] = qf               * (1.f / 64.f) + bw;
        m[1][h] = (qf - q63)       * (1.f / 63.f) + bw;
        m[2][h] = (qf - q0)        * (1.f / 63.f) + bw;
        m[3][h] = (qf - q62 - q63) * (1.f / 62.f) + bw;
        m[4][h] = (qf - q0  - q63) * (1.f / 62.f) + bw;
        m[5][h] = (qf - q0  - q1)  * (1.f / 62.f) + bw;
    }
    __syncthreads();

    if (tid < H_) {
        const int o = tid;
        float a1 = cb1[o], a2 = cb2[o], a3 = cb3[o];
        for (int i = 0; i < H_; ++i) {
            a1 += cw1[o * H_ + i] * m[0][i];
            const float* c2 = cw2 + (o * H_ + i) * 2;
            a2 += c2[0] * m[1][i] + c2[1] * m[2][i];
            const float* c3 = cw3 + (o * H_ + i) * 3;
            a3 += c3[0] * m[3][i] + c3[1] * m[4][i] + c3[2] * m[5][i];
        }
        reps_sh[o] = (tanhf(a1) + tanhf(a2) + tanhf(a3)) * (1.f / 3.f);
    }
    __syncthreads();

    if (tid < 3 * H_) {
        const int g = tid / H_, o = tid % H_;
        const float* Wg = (g == 0) ? Wi : (g == 1) ? Wf : Wr;
        const float* bg = (g == 0) ? bi : (g == 1) ? bf : br;
        float acc = bg[o];
        for (int j = 0; j < H_; ++j) acc += Wg[o * H_ + j] * reps_sh[j];
        Xout[(g * S_ + s) * H_ + o] = acc;
    }
}

// ---------------------------------------------------------------------------
// Kernel 2 (v6): 4-wave column-split GRNN scan.
// Lesson R8/R11/R12/R13: the allocator caps VGPRs at 64-132 regardless of
// occupancy hints and sinks large loop-invariant arrays into the loop. So
// make the slice SMALL: wave w holds cols [13w, 13w+13) of Ui/Uf/Ur for its
// row -> 39 U regs/lane (+~20 temps), resident under even a 64-VGPR budget.
// Partials: part[parity][gate][o][4] -> one ds_read_b128 per gate. One
// barrier/step (parity double-buffer). Gates/h redundant in all 4 waves.
// ---------------------------------------------------------------------------
#define JW 13   // columns per wave (4*13 = 52 >= 50; tail guarded)

__device__ __forceinline__ float tanh_fast(float x) {
    float e = __expf(2.f * x);
    return (e - 1.f) / (e + 1.f);
}

__device__ __forceinline__ float bcast(float v, int lane) {
    return __int_as_float(__builtin_amdgcn_readlane(__float_as_int(v), lane));
}

__global__ __launch_bounds__(256, 1) void k_scan(
    const float* __restrict__ X,   // [3][S_][H_]
    const float* __restrict__ Ui, const float* __restrict__ Uf,
    const float* __restrict__ Ur,
    const float* __restrict__ Wout, const float* __restrict__ bout,
    float* __restrict__ out)
{
    const int tid = threadIdx.x;
    const int w   = tid >> 6;                 // wave: 0..3
    const int o   = tid & 63;
    const int ro  = (o < H_) ? o : (H_ - 1);  // clamped row, all lanes in-bounds
    const int jlo = w * JW;                   // this wave's column window

    // part[parity][gate][o][wave] ; [o][4] rows are 16B-aligned for b128 read
    __shared__ float part[2][3][64][4];

    float ua[JW], ub[JW], uc[JW];
    {
        const float* Uir = Ui + ro * H_;
        const float* Ufr = Uf + ro * H_;
        const float* Urr = Ur + ro * H_;
        #pragma unroll
        for (int jj = 0; jj < JW; ++jj) {
            const int j = jlo + jj;
            const bool ok = (j < H_);
            ua[jj] = ok ? Uir[j] : 0.f;
            ub[jj] = ok ? Ufr[j] : 0.f;
            uc[jj] = ok ? Urr[j] : 0.f;
        }
    }

    float h  = 0.f;                            // lane o holds h[o] (all waves)
    float xi = X[(0 * S_ + 0) * H_ + ro];
    float xf = X[(1 * S_ + 0) * H_ + ro];
    float xr = X[(2 * S_ + 0) * H_ + ro];

    int p = 0;
    for (int t = 0; t < S_; ++t) {
        const int tn = (t + 1 < S_) ? (t + 1) : (S_ - 1);   // clamped prefetch
        float nxi = X[(0 * S_ + tn) * H_ + ro];
        float nxf = X[(1 * S_ + tn) * H_ + ro];
        float nxr = X[(2 * S_ + tn) * H_ + ro];

        // partial dots over this wave's column window
        float pi = 0.f, pf = 0.f, pr = 0.f;
        #pragma unroll
        for (int jj = 0; jj < JW; ++jj) {
            const int j  = jlo + jj;
            const int jl = (j < H_) ? j : (H_ - 1);  // wave-uniform SGPR index
            float hj = bcast(h, jl);                 // garbage*0 stays finite
            pi += ua[jj] * hj;
            pf += ub[jj] * hj;
            pr += uc[jj] * hj;
        }
        part[p][0][o][w] = pi;
        part[p][1][o][w] = pf;
        part[p][2][o][w] = pr;
        __syncthreads();

        const float4 vi = *reinterpret_cast<const float4*>(&part[p][0][o][0]);
        const float4 vf = *reinterpret_cast<const float4*>(&part[p][1][o][0]);
        const float4 vr = *reinterpret_cast<const float4*>(&part[p][2][o][0]);
        float ai = xi + (vi.x + vi.y) + (vi.z + vi.w);
        float af = xf + (vf.x + vf.y) + (vf.z + vf.w);
        float ar = xr + (vr.x + vr.y) + (vr.z + vr.w);

        float gi = 1.f / (1.f + __expf(-ai));
        float gf = 1.f / (1.f + __expf(-af));
        float gg = tanh_fast(ar);
        h = tanh_fast(gi * gg + gf * h);       // identical in all waves

        xi = nxi; xf = nxf; xr = nxr;
        p ^= 1;                                // double buffer: no 2nd barrier
    }

    // output head (all waves compute identically; tid 0 stores)
    float logit = (o < OUT_) ? bout[o] : 0.f;
    const float* wrow = Wout + ((o < OUT_) ? o : 0) * H_;
    #pragma unroll
    for (int j = 0; j < H_; ++j) {
        float hj = bcast(h, j);
        logit += wrow[j] * hj;
    }
    float l0 = bcast(logit, 0), l1 = bcast(logit, 1), l2 = bcast(logit, 2),
          l3 = bcast(logit, 3), l4 = bcast(logit, 4);
    float mx = fmaxf(fmaxf(fmaxf(l0, l1), fmaxf(l2, l3)), l4);
    float e0 = __expf(l0 - mx), e1 = __expf(l1 - mx), e2 = __expf(l2 - mx),
          e3 = __expf(l3 - mx), e4 = __expf(l4 - mx);
    float s = e0 + e1 + e2 + e3 + e4;
    if (tid == 0) {
        out[0] = e0 / s; out[1] = e1 / s; out[2] = e2 / s;
        out[3] = e3 / s; out[4] = e4 / s;
    }
}

extern "C" void kernel_launch(void* const* d_in, const int* in_sizes, int n_in,
                              void* d_out, int out_size, void* d_ws, size_t ws_size,
                              hipStream_t stream) {
    (void)in_sizes; (void)n_in; (void)out_size; (void)ws_size;

    const int*   doc    = (const int*)  d_in[0];
    const float* emb    = (const float*)d_in[1];
    const float* w_word = (const float*)d_in[2];
    const float* b_word = (const float*)d_in[3];
    const float* cw1    = (const float*)d_in[4];
    const float* cb1    = (const float*)d_in[5];
    const float* cw2    = (const float*)d_in[6];
    const float* cb2    = (const float*)d_in[7];
    const float* cw3    = (const float*)d_in[8];
    const float* cb3    = (const float*)d_in[9];
    const float* Wi     = (const float*)d_in[10];
    const float* Ui     = (const float*)d_in[11];
    const float* bi     = (const float*)d_in[12];
    const float* Wf     = (const float*)d_in[13];
    const float* Uf     = (const float*)d_in[14];
    const float* bf     = (const float*)d_in[15];
    const float* Wr     = (const float*)d_in[16];
    const float* Ur     = (const float*)d_in[17];
    const float* br     = (const float*)d_in[18];
    const float* Wout   = (const float*)d_in[19];
    const float* bout   = (const float*)d_in[20];

    float* X = (float*)d_ws;                 // [3][S_][H_] = 76.8 KB
    float* out = (float*)d_out;

    k_sent<<<S_, 256, 0, stream>>>(doc, emb, w_word, b_word,
                                   cw1, cb1, cw2, cb2, cw3, cb3,
                                   Wi, bi, Wf, bf, Wr, br, X);
    k_scan<<<1, 256, 0, stream>>>(X, Ui, Uf, Ur, Wout, bout, out);
}